// Round 3
// baseline (149.736 us; speedup 1.0000x reference)
//
#include <hip/hip_runtime.h>

// Net_3152505995417: tiny GNN forward (N=116, E=6670, HID=64, EDIM=5).
// Algebraic collapses (exact, absmax=0 in R1/R2):
//  * node_conv: out = D @ (Hv@W) + b, D[i,j] = d[eid(i,j)] off-diag (symmetric).
//  * edge_conv: out[e=(a,b),k] = dv[a]*(S[a,k]-Gp[e,k]) + dv[b]*(S[b,k]-Gp[e,k]) + be,
//      Gp[f] = G[f]/(max(dv[c],dv[d],0)+eps) for f=(c,d), S[i] = sum_{f∋i} Gp[f].
// R3: single persistent kernel, 29 blocks x 256 threads, 5 device-scope atomic
//     grid barriers. Dispatch count 6 -> 2 (memset of barrier flags + kernel);
//     my controllable time is now one ~6-10us kernel instead of 6 launches.
//     Barrier safety: 29 blocks << 256 CUs -> co-resident; atomicAdd is
//     device-scope [m20]; spin uses AGENT-scope atomic load (bypasses L1);
//     __threadfence gives agent release/acquire around arrival.
//     rocprof counter-replay without the memset falls through barriers
//     (counters already >= target) -- no hang, and validation uses the full
//     captured sequence.

#define NN   116
#define EE   6670
#define HID  64
#define EDIM 5
#define OUTD 4
#define ENC  122
#define EPSF 1e-10f
#define NH   (NN*HID)   // 7424
#define NB   29         // blocks

__device__ __forceinline__ int eid_ij(int i, int j) {
    int a = i < j ? i : j;
    int b = i < j ? j : i;
    return a*NN - ((a*(a+1)) >> 1) + (b - a - 1);   // triu k=1 row-major
}

__device__ __forceinline__ void gridbar(unsigned* bar, unsigned target) {
    __syncthreads();
    if (threadIdx.x == 0) {
        __threadfence();                       // agent-scope release
        atomicAdd(bar, 1u);                    // device scope by default
        while (__hip_atomic_load(bar, __ATOMIC_RELAXED, __HIP_MEMORY_SCOPE_AGENT) < target)
            __builtin_amdgcn_s_sleep(2);
        __threadfence();                       // agent-scope acquire
    }
    __syncthreads();
}

__global__ __launch_bounds__(256) void fused(
    const float* __restrict__ enc, const float* __restrict__ ea,
    const int* __restrict__ eidx,
    const float* __restrict__ W_enc, const float* __restrict__ b_enc,
    const float* __restrict__ W1, const float* __restrict__ b1,
    const float* __restrict__ p1, const float* __restrict__ We,
    const float* __restrict__ be, const float* __restrict__ pe,
    const float* __restrict__ W2, const float* __restrict__ b2,
    const float* __restrict__ p2, const float* __restrict__ Wl,
    const float* __restrict__ bl,
    float* __restrict__ Y1, float* __restrict__ Y2,
    float* __restrict__ d1, float* __restrict__ d2,
    float* __restrict__ G,  float* __restrict__ dv,
    float* __restrict__ S,  float* __restrict__ P,
    unsigned* __restrict__ bar,
    float* __restrict__ out)
{
    __shared__ __align__(16) float sY[NH];     // 29696 B (Y1, then Y2)
    __shared__ __align__(16) float sD[EE];     // 26680 B (d1, then d2)
    __shared__ float sRow[4*HID];              // x-rows / dv cache / pool partials
    const int tid  = threadIdx.x;
    const int w    = tid >> 6, lane = tid & 63;
    const int node = blockIdx.x*4 + w;         // 0..115, always valid (29*4=116)
    const int gt   = blockIdx.x*256 + tid;     // 0..7423

    // ---- Stage A: X=enc@W_enc+b_enc -> Y1=X@W1 (wave per node); d1, G (all threads); zero P.
    {
        float x = b_enc[lane];
        const float* er = enc + node*ENC;
        #pragma unroll 4
        for (int k = 0; k < ENC; ++k) x = fmaf(er[k], W_enc[k*HID + lane], x);
        sRow[w*HID + lane] = x;
        __syncthreads();
        float y = 0.f;
        const float* xr = sRow + w*HID;
        #pragma unroll 8
        for (int k = 0; k < HID; ++k) y = fmaf(xr[k], W1[k*HID + lane], y);
        Y1[node*HID + lane] = y;

        for (int u = gt; u < EE + EE*EDIM; u += NB*256) {
            if (u < EE) {
                const float* r = ea + u*EDIM;
                float a0 = 0.f;
                #pragma unroll
                for (int k = 0; k < EDIM; ++k) a0 = fmaf(r[k], p1[k], a0);
                d1[u] = a0;
            } else {
                int idx = u - EE;
                int e = idx / EDIM, k = idx - e*EDIM;
                const float* r = ea + e*EDIM;
                float a0 = 0.f;
                #pragma unroll
                for (int m = 0; m < EDIM; ++m) a0 = fmaf(fmaxf(r[m], 0.f), We[m*EDIM + k], a0);
                G[idx] = a0;
            }
        }
        if (gt < HID) P[gt] = 0.f;
    }
    gridbar(bar + 0, NB);

    // ---- Stage B: x2 = relu(D1@Y1 + b1); dv = x2@pe; Y2 = x2@W2. LDS-staged, branchless.
    {
        const float4* g4 = (const float4*)Y1; float4* s4 = (float4*)sY;
        for (int u = tid; u < NH/4; u += 256) s4[u] = g4[u];
        const float2* g2 = (const float2*)d1; float2* s2 = (float2*)sD;
        for (int u = tid; u < EE/2; u += 256) s2[u] = g2[u];
        __syncthreads();
        float acc = b1[lane];
        #pragma unroll 4
        for (int j = 0; j < NN; ++j) {
            int jj = (j == node) ? (j ^ 1) : j;
            float wgt = (j == node) ? 0.f : sD[eid_ij(node, jj)];
            acc = fmaf(wgt, sY[jj*HID + lane], acc);
        }
        float v = fmaxf(acc, 0.f);
        float r = v * pe[lane];
        #pragma unroll
        for (int off = 32; off > 0; off >>= 1) r += __shfl_xor(r, off, 64);
        if (lane == 0) dv[node] = r;
        __syncthreads();                 // sRow reuse (x-row slot)
        sRow[w*HID + lane] = v;
        __syncthreads();
        float y = 0.f;
        const float* xr = sRow + w*HID;
        #pragma unroll 8
        for (int k = 0; k < HID; ++k) y = fmaf(xr[k], W2[k*HID + lane], y);
        Y2[node*HID + lane] = y;
    }
    gridbar(bar + 1, NB);

    // ---- Stage C: S[i,k] = sum_{j!=i} G[eid(i,j),k]/(max(dv[i],dv[j],0)+eps).
    //      dv cached in sRow; 580 (i,k) pairs = 116 waves x 5; lanes split j.
    {
        if (tid < NN) sRow[tid] = dv[tid];
        __syncthreads();
        #pragma unroll
        for (int rep = 0; rep < EDIM; ++rep) {
            int p = node + rep*NN;              // 0..579
            int i = p / EDIM, k = p - i*EDIM;
            float di = sRow[i];
            float acc = 0.f;
            #pragma unroll
            for (int half = 0; half < 2; ++half) {
                int j = lane + half*64;
                if (j < NN && j != i) {
                    float cm = fmaxf(fmaxf(di, sRow[j]), 0.f) + EPSF;
                    acc += G[eid_ij(i, j)*EDIM + k] / cm;
                }
            }
            #pragma unroll
            for (int off = 32; off > 0; off >>= 1) acc += __shfl_xor(acc, off, 64);
            if (lane == 0) S[p] = acc;
        }
    }
    gridbar(bar + 2, NB);

    // ---- Stage D: per-edge d2 (thread per edge; dv still cached in sRow).
    if (gt < EE) {
        const int a = eidx[gt], b = eidx[EE + gt];
        const float da = sRow[a], db = sRow[b];
        const float rc = 1.f / (fmaxf(fmaxf(da, db), 0.f) + EPSF);
        float acc = 0.f;
        #pragma unroll
        for (int kk = 0; kk < EDIM; ++kk) {
            float gp = G[gt*EDIM + kk] * rc;
            float v = fmaf(da, S[a*EDIM + kk] - gp, fmaf(db, S[b*EDIM + kk] - gp, be[kk]));
            acc = fmaf(fmaxf(v, 0.f), p2[kk], acc);
        }
        d2[gt] = acc;
    }
    gridbar(bar + 3, NB);

    // ---- Stage E: x3 = D2@Y2 + b2; block-partial pool -> atomicAdd P.
    {
        const float4* g4 = (const float4*)Y2; float4* s4 = (float4*)sY;
        for (int u = tid; u < NH/4; u += 256) s4[u] = g4[u];
        const float2* g2 = (const float2*)d2; float2* s2 = (float2*)sD;
        for (int u = tid; u < EE/2; u += 256) s2[u] = g2[u];
        __syncthreads();
        float acc = b2[lane];
        #pragma unroll 4
        for (int j = 0; j < NN; ++j) {
            int jj = (j == node) ? (j ^ 1) : j;
            float wgt = (j == node) ? 0.f : sD[eid_ij(node, jj)];
            acc = fmaf(wgt, sY[jj*HID + lane], acc);
        }
        sRow[w*HID + lane] = acc;
        __syncthreads();
        if (w == 0) {
            float s4v = sRow[lane] + sRow[HID + lane] + sRow[2*HID + lane] + sRow[3*HID + lane];
            atomicAdd(&P[lane], s4v);
        }
    }
    gridbar(bar + 4, NB);

    // ---- Stage F: out = (P/N) @ Wl + bl (block 0, wave 0).
    if (blockIdx.x == 0 && w == 0) {
        float val = P[lane] * (1.0f / NN);
        float res[OUTD];
        #pragma unroll
        for (int o = 0; o < OUTD; ++o) {
            float r = val * Wl[lane*OUTD + o];
            #pragma unroll
            for (int off = 32; off > 0; off >>= 1) r += __shfl_xor(r, off, 64);
            res[o] = r;
        }
        if (lane < OUTD) out[lane] = res[lane] + bl[lane];
    }
}

extern "C" void kernel_launch(void* const* d_in, const int* in_sizes, int n_in,
                              void* d_out, int out_size, void* d_ws, size_t ws_size,
                              hipStream_t stream)
{
    const float* enc   = (const float*)d_in[0];
    const float* ea    = (const float*)d_in[1];
    const int*   eidx  = (const int*)  d_in[2];
    const float* W_enc = (const float*)d_in[3];
    const float* b_enc = (const float*)d_in[4];
    const float* W1    = (const float*)d_in[5];
    const float* b1    = (const float*)d_in[6];
    const float* p1    = (const float*)d_in[7];
    const float* We    = (const float*)d_in[8];
    const float* be    = (const float*)d_in[9];
    const float* pe    = (const float*)d_in[10];
    const float* W2    = (const float*)d_in[11];
    const float* b2    = (const float*)d_in[12];
    const float* p2    = (const float*)d_in[13];
    const float* Wl    = (const float*)d_in[14];
    const float* bl    = (const float*)d_in[15];
    float* ws = (float*)d_ws;

    // Workspace layout (floats, 16B-aligned chunks):
    float* Y1 = ws;                    // NH   = 7424
    float* Y2 = ws + 7424;             // NH
    float* d1 = ws + 14848;            // EE -> pad 6672
    float* d2 = ws + 21520;            // EE -> pad 6672
    float* G  = ws + 28192;            // EE*EDIM = 33350 -> pad 33352
    float* dv = ws + 61544;            // NN -> pad 120
    float* S  = ws + 61664;            // 580 -> pad 584
    float* P  = ws + 62248;            // 64
    unsigned* bar = (unsigned*)(ws + 62312);   // 5 counters
    float* out = (float*)d_out;

    hipMemsetAsync(bar, 0, 5*sizeof(unsigned), stream);
    fused<<<NB, 256, 0, stream>>>(enc, ea, eidx, W_enc, b_enc, W1, b1, p1, We,
                                  be, pe, W2, b2, p2, Wl, bl,
                                  Y1, Y2, d1, d2, G, dv, S, P, bar, out);
}

// Round 4
// 149.718 us; speedup vs baseline: 1.0001x; 1.0001x over previous
//
#include <hip/hip_runtime.h>

// Net_3152505995417: tiny GNN forward (N=116, E=6670, HID=64, EDIM=5).
// Algebraic collapses (exact, absmax=0 since R1):
//  * node_conv: out = D @ (Hv@W) + b, D[i,j] = d[eid(i,j)] off-diag (symmetric).
//  * edge_conv: out[e=(a,b),k] = dv[a]*(S[a,k]-Gp[e,k]) + dv[b]*(S[b,k]-Gp[e,k]) + be,
//      Gp[f] = G[f]/(max(dv[c],dv[d],0)+eps) for f=(c,d), S[i] = sum_{f∋i} Gp[f].
// R4: SAME persistent 29-block body as R3; ONLY the grid barrier changed.
//   R3 post-mortem: 5 barriers cost ~13.6us each = 29 serialized atomicAdd RMWs
//   on one contended line (~0.42us per cross-XCD RMW). Fix: flag-array barrier —
//   per-block epoch flags on distinct cachelines (parallel stores, no RMW),
//   block 0 polls all flags with one 29-lane wave, publishes `go`; others poll
//   `go` only. Epoch values are monotone so one memset serves all 5 barriers,
//   and a counter-replay without the memset falls through (0xAAAA.. >= ep, no hang).

#define NN   116
#define EE   6670
#define HID  64
#define EDIM 5
#define OUTD 4
#define ENC  122
#define EPSF 1e-10f
#define NH   (NN*HID)   // 7424
#define NB   29         // blocks
#define FSTR 16         // flag stride in uints (64B = one cacheline)

__device__ __forceinline__ int eid_ij(int i, int j) {
    int a = i < j ? i : j;
    int b = i < j ? j : i;
    return a*NN - ((a*(a+1)) >> 1) + (b - a - 1);   // triu k=1 row-major
}

// Flag-array grid barrier. flags[b*FSTR] per block, go at flags[NB*FSTR].
// ep is the barrier's epoch (1-based, strictly increasing within the launch).
__device__ __forceinline__ void gridbar(unsigned* flags, unsigned ep) {
    __syncthreads();
    unsigned* go = flags + NB*FSTR;
    if (threadIdx.x == 0) {
        __threadfence();   // release: push this block's stores to coherence point
        __hip_atomic_store(flags + blockIdx.x*FSTR, ep,
                           __ATOMIC_RELAXED, __HIP_MEMORY_SCOPE_AGENT);
    }
    if (blockIdx.x == 0) {
        if (threadIdx.x < 64) {
            if (threadIdx.x < NB) {   // lane l watches block l's flag (parallel loads)
                while (__hip_atomic_load(flags + threadIdx.x*FSTR,
                                         __ATOMIC_RELAXED, __HIP_MEMORY_SCOPE_AGENT) < ep)
                    __builtin_amdgcn_s_sleep(1);
            }
            if (threadIdx.x == 0)
                __hip_atomic_store(go, ep, __ATOMIC_RELAXED, __HIP_MEMORY_SCOPE_AGENT);
        }
    } else if (threadIdx.x == 0) {
        while (__hip_atomic_load(go, __ATOMIC_RELAXED, __HIP_MEMORY_SCOPE_AGENT) < ep)
            __builtin_amdgcn_s_sleep(1);
    }
    if (threadIdx.x == 0) __threadfence();   // acquire: invalidate stale cached lines
    __syncthreads();
}

__global__ __launch_bounds__(256) void fused(
    const float* __restrict__ enc, const float* __restrict__ ea,
    const int* __restrict__ eidx,
    const float* __restrict__ W_enc, const float* __restrict__ b_enc,
    const float* __restrict__ W1, const float* __restrict__ b1,
    const float* __restrict__ p1, const float* __restrict__ We,
    const float* __restrict__ be, const float* __restrict__ pe,
    const float* __restrict__ W2, const float* __restrict__ b2,
    const float* __restrict__ p2, const float* __restrict__ Wl,
    const float* __restrict__ bl,
    float* __restrict__ Y1, float* __restrict__ Y2,
    float* __restrict__ d1, float* __restrict__ d2,
    float* __restrict__ G,  float* __restrict__ dv,
    float* __restrict__ S,  float* __restrict__ P,
    unsigned* __restrict__ flags,
    float* __restrict__ out)
{
    __shared__ __align__(16) float sY[NH];     // 29696 B (Y1, then Y2)
    __shared__ __align__(16) float sD[EE];     // 26680 B (d1, then d2)
    __shared__ float sRow[4*HID];              // x-rows / dv cache / pool partials
    const int tid  = threadIdx.x;
    const int w    = tid >> 6, lane = tid & 63;
    const int node = blockIdx.x*4 + w;         // 0..115 (29*4=116, always valid)
    const int gt   = blockIdx.x*256 + tid;     // 0..7423

    // ---- Stage A: X=enc@W_enc+b_enc -> Y1=X@W1 (wave per node); d1, G (grid-strided); zero P.
    {
        float x = b_enc[lane];
        const float* er = enc + node*ENC;
        #pragma unroll 4
        for (int k = 0; k < ENC; ++k) x = fmaf(er[k], W_enc[k*HID + lane], x);
        sRow[w*HID + lane] = x;
        __syncthreads();
        float y = 0.f;
        const float* xr = sRow + w*HID;
        #pragma unroll 8
        for (int k = 0; k < HID; ++k) y = fmaf(xr[k], W1[k*HID + lane], y);
        Y1[node*HID + lane] = y;

        for (int u = gt; u < EE + EE*EDIM; u += NB*256) {
            if (u < EE) {
                const float* r = ea + u*EDIM;
                float a0 = 0.f;
                #pragma unroll
                for (int k = 0; k < EDIM; ++k) a0 = fmaf(r[k], p1[k], a0);
                d1[u] = a0;
            } else {
                int idx = u - EE;
                int e = idx / EDIM, k = idx - e*EDIM;
                const float* r = ea + e*EDIM;
                float a0 = 0.f;
                #pragma unroll
                for (int m = 0; m < EDIM; ++m) a0 = fmaf(fmaxf(r[m], 0.f), We[m*EDIM + k], a0);
                G[idx] = a0;
            }
        }
        if (gt < HID) P[gt] = 0.f;
    }
    gridbar(flags, 1u);

    // ---- Stage B: x2 = relu(D1@Y1 + b1); dv = x2@pe; Y2 = x2@W2. LDS-staged, branchless.
    {
        const float4* g4 = (const float4*)Y1; float4* s4 = (float4*)sY;
        for (int u = tid; u < NH/4; u += 256) s4[u] = g4[u];
        const float2* g2 = (const float2*)d1; float2* s2 = (float2*)sD;
        for (int u = tid; u < EE/2; u += 256) s2[u] = g2[u];
        __syncthreads();
        float acc = b1[lane];
        #pragma unroll 4
        for (int j = 0; j < NN; ++j) {
            int jj = (j == node) ? (j ^ 1) : j;
            float wgt = (j == node) ? 0.f : sD[eid_ij(node, jj)];
            acc = fmaf(wgt, sY[jj*HID + lane], acc);
        }
        float v = fmaxf(acc, 0.f);
        float r = v * pe[lane];
        #pragma unroll
        for (int off = 32; off > 0; off >>= 1) r += __shfl_xor(r, off, 64);
        if (lane == 0) dv[node] = r;
        __syncthreads();                 // sRow reuse (x-row slot)
        sRow[w*HID + lane] = v;
        __syncthreads();
        float y = 0.f;
        const float* xr = sRow + w*HID;
        #pragma unroll 8
        for (int k = 0; k < HID; ++k) y = fmaf(xr[k], W2[k*HID + lane], y);
        Y2[node*HID + lane] = y;
    }
    gridbar(flags, 2u);

    // ---- Stage C: S[i,k] = sum_{j!=i} G[eid(i,j),k]/(max(dv[i],dv[j],0)+eps).
    //      dv cached in sRow; 580 (i,k) pairs = 116 waves x 5; lanes split j.
    {
        if (tid < NN) sRow[tid] = dv[tid];
        __syncthreads();
        #pragma unroll
        for (int rep = 0; rep < EDIM; ++rep) {
            int p = node + rep*NN;              // 0..579
            int i = p / EDIM, k = p - i*EDIM;
            float di = sRow[i];
            float acc = 0.f;
            #pragma unroll
            for (int half = 0; half < 2; ++half) {
                int j = lane + half*64;
                if (j < NN && j != i) {
                    float cm = fmaxf(fmaxf(di, sRow[j]), 0.f) + EPSF;
                    acc += G[eid_ij(i, j)*EDIM + k] / cm;
                }
            }
            #pragma unroll
            for (int off = 32; off > 0; off >>= 1) acc += __shfl_xor(acc, off, 64);
            if (lane == 0) S[p] = acc;
        }
    }
    gridbar(flags, 3u);

    // ---- Stage D: per-edge d2 (thread per edge; dv still cached in sRow).
    if (gt < EE) {
        const int a = eidx[gt], b = eidx[EE + gt];
        const float da = sRow[a], db = sRow[b];
        const float rc = 1.f / (fmaxf(fmaxf(da, db), 0.f) + EPSF);
        float acc = 0.f;
        #pragma unroll
        for (int kk = 0; kk < EDIM; ++kk) {
            float gp = G[gt*EDIM + kk] * rc;
            float v = fmaf(da, S[a*EDIM + kk] - gp, fmaf(db, S[b*EDIM + kk] - gp, be[kk]));
            acc = fmaf(fmaxf(v, 0.f), p2[kk], acc);
        }
        d2[gt] = acc;
    }
    gridbar(flags, 4u);

    // ---- Stage E: x3 = D2@Y2 + b2; block-partial pool -> atomicAdd P.
    {
        const float4* g4 = (const float4*)Y2; float4* s4 = (float4*)sY;
        for (int u = tid; u < NH/4; u += 256) s4[u] = g4[u];
        const float2* g2 = (const float2*)d2; float2* s2 = (float2*)sD;
        for (int u = tid; u < EE/2; u += 256) s2[u] = g2[u];
        __syncthreads();
        float acc = b2[lane];
        #pragma unroll 4
        for (int j = 0; j < NN; ++j) {
            int jj = (j == node) ? (j ^ 1) : j;
            float wgt = (j == node) ? 0.f : sD[eid_ij(node, jj)];
            acc = fmaf(wgt, sY[jj*HID + lane], acc);
        }
        sRow[w*HID + lane] = acc;
        __syncthreads();
        if (w == 0) {
            float s4v = sRow[lane] + sRow[HID + lane] + sRow[2*HID + lane] + sRow[3*HID + lane];
            atomicAdd(&P[lane], s4v);
        }
    }
    gridbar(flags, 5u);

    // ---- Stage F: out = (P/N) @ Wl + bl (block 0, wave 0).
    if (blockIdx.x == 0 && w == 0) {
        float val = P[lane] * (1.0f / NN);
        float res[OUTD];
        #pragma unroll
        for (int o = 0; o < OUTD; ++o) {
            float r = val * Wl[lane*OUTD + o];
            #pragma unroll
            for (int off = 32; off > 0; off >>= 1) r += __shfl_xor(r, off, 64);
            res[o] = r;
        }
        if (lane < OUTD) out[lane] = res[lane] + bl[lane];
    }
}

extern "C" void kernel_launch(void* const* d_in, const int* in_sizes, int n_in,
                              void* d_out, int out_size, void* d_ws, size_t ws_size,
                              hipStream_t stream)
{
    const float* enc   = (const float*)d_in[0];
    const float* ea    = (const float*)d_in[1];
    const int*   eidx  = (const int*)  d_in[2];
    const float* W_enc = (const float*)d_in[3];
    const float* b_enc = (const float*)d_in[4];
    const float* W1    = (const float*)d_in[5];
    const float* b1    = (const float*)d_in[6];
    const float* p1    = (const float*)d_in[7];
    const float* We    = (const float*)d_in[8];
    const float* be    = (const float*)d_in[9];
    const float* pe    = (const float*)d_in[10];
    const float* W2    = (const float*)d_in[11];
    const float* b2    = (const float*)d_in[12];
    const float* p2    = (const float*)d_in[13];
    const float* Wl    = (const float*)d_in[14];
    const float* bl    = (const float*)d_in[15];
    float* ws = (float*)d_ws;

    // Workspace layout (floats, 16B-aligned chunks):
    float* Y1 = ws;                    // 7424
    float* Y2 = ws + 7424;             // 7424
    float* d1 = ws + 14848;            // 6670 -> pad 6672
    float* d2 = ws + 21520;            // 6672
    float* G  = ws + 28192;            // 33350 -> pad 33352
    float* dv = ws + 61544;            // 116 -> pad 120
    float* S  = ws + 61664;            // 580 -> pad 584
    float* P  = ws + 62248;            // 64 -> pad 88 (to 64B-aligned 62336)
    unsigned* flags = (unsigned*)(ws + 62336);  // (NB+1)*FSTR uints, 64B-spaced
    float* out = (float*)d_out;

    hipMemsetAsync(flags, 0, (NB + 1) * FSTR * sizeof(unsigned), stream);
    fused<<<NB, 256, 0, stream>>>(enc, ea, eidx, W_enc, b_enc, W1, b1, p1, We,
                                  be, pe, W2, b2, p2, Wl, bl,
                                  Y1, Y2, d1, d2, G, dv, S, P, flags, out);
}